// Round 1
// baseline (68.064 us; speedup 1.0000x reference)
//
#include <hip/hip_runtime.h>
#include <math.h>

#define SRATE   24000.0
#define NB      8
#define NT      48000
#define NH      60
#define NC      100
#define NFMT    5
#define CT      256                      // timesteps per block
#define NCH     ((NT + CT - 1) / CT)     // 188 chunks per batch
#define TWO_PI  6.283185307179586476925286766559

// ---------------- kernel 1: per-chunk f0 sums (double) ----------------
__global__ __launch_bounds__(CT) void k_partial(const float* __restrict__ f0,
                                                double* __restrict__ part) {
    int b = blockIdx.y, ch = blockIdx.x;
    int t = ch * CT + threadIdx.x;
    double q = (t < NT) ? (double)f0[b * NT + t] : 0.0;
    #pragma unroll
    for (int off = 32; off > 0; off >>= 1)
        q += __shfl_down(q, off, 64);
    __shared__ double wsum[CT / 64];
    int lane = threadIdx.x & 63, wid = threadIdx.x >> 6;
    if (lane == 0) wsum[wid] = q;
    __syncthreads();
    if (threadIdx.x == 0) {
        double s = 0.0;
        for (int i = 0; i < CT / 64; ++i) s += wsum[i];
        part[b * NCH + ch] = s;
    }
}

// ------- kernel 2: per-batch exclusive scan of chunk sums + final phase -------
__global__ __launch_bounds__(64) void k_scan(const double* __restrict__ part,
                                             double* __restrict__ offs,
                                             const float* __restrict__ initp,
                                             float* __restrict__ outf) {
    int b = blockIdx.x;
    int lane = threadIdx.x;
    double carry = 0.0;
    for (int base = 0; base < NCH; base += 64) {
        int i = base + lane;
        double v = (i < NCH) ? part[b * NCH + i] : 0.0;
        double inc = v;
        #pragma unroll
        for (int off = 1; off < 64; off <<= 1) {
            double n = __shfl_up(inc, off, 64);
            if (lane >= off) inc += n;
        }
        double excl = __shfl_up(inc, 1, 64);
        if (lane == 0) excl = 0.0;
        if (i < NCH) offs[b * NCH + i] = carry + excl;
        carry += __shfl(inc, 63, 64);
    }
    if (lane == 0) {
        // final_phase = (2*pi*cumsum_total/SR + init) mod 2*pi
        double rev = carry / SRATE + (double)initp[b] * (1.0 / TWO_PI);
        double fr = rev - floor(rev);
        outf[b] = (float)(fr * TWO_PI);
    }
}

// ---------------- kernel 3: main synthesis ----------------
__global__ __launch_bounds__(CT) void k_main(const float* __restrict__ f0,
                                             const float* __restrict__ amps,
                                             const float* __restrict__ ffq,
                                             const float* __restrict__ fbw,
                                             const float* __restrict__ fam,
                                             const float* __restrict__ initp,
                                             const double* __restrict__ offs,
                                             float* __restrict__ out) {
    int b = blockIdx.y, ch = blockIdx.x;
    int tid = threadIdx.x;
    int t = ch * CT + tid;
    bool valid = t < NT;
    float f0v = valid ? f0[b * NT + t] : 0.0f;

    // in-block inclusive scan of f0 (double)
    int lane = tid & 63, wid = tid >> 6;
    double inc = (double)f0v;
    #pragma unroll
    for (int off = 1; off < 64; off <<= 1) {
        double n = __shfl_up(inc, off, 64);
        if (lane >= off) inc += n;
    }
    __shared__ double wsum[CT / 64];
    if (lane == 63) wsum[wid] = inc;
    __syncthreads();
    double pre = offs[b * NCH + ch];
    #pragma unroll
    for (int i = 0; i < CT / 64; ++i)
        if (i < wid) pre += wsum[i];
    if (!valid) return;

    // phase in revolutions, reduced mod 1 in double
    double rev = (pre + inc) / SRATE + (double)initp[b] * (1.0 / TWO_PI);
    double fr = rev - floor(rev);
    float rev_f = (float)fr;

    // formant track linear interpolation (align_corners=True)
    double srcd = (double)t * (99.0 / 47999.0);
    int i0 = (int)floor(srcd);
    if (i0 > NC - 2) i0 = NC - 2;
    if (i0 < 0) i0 = 0;
    float frac = (float)(srcd - (double)i0);
    float omf = 1.0f - frac;

    const float* Fq = ffq + (b * NC + i0) * NFMT;
    const float* Bw = fbw + (b * NC + i0) * NFMT;
    const float* Am = fam + (b * NC + i0) * NFMT;
    float freq[NFMT], c1[NFMT], c2[NFMT];
    #pragma unroll
    for (int f = 0; f < NFMT; ++f) {
        float fq = Fq[f] * omf + Fq[NFMT + f] * frac;
        float bw = Bw[f] * omf + Bw[NFMT + f] * frac;
        float am = Am[f] * omf + Am[NFMT + f] * frac;
        freq[f] = fq;
        c2[f] = bw * bw;
        c1[f] = am * bw * bw;
    }

    const float4* a4 = (const float4*)(amps + ((size_t)(b * NT) + (size_t)t) * NH);
    float acc = 0.0f;
    #pragma unroll
    for (int hq = 0; hq < NH / 4; ++hq) {
        // all harmonics in this quad (and beyond) are nyquist-masked -> done
        if (f0v * (float)(hq * 4 + 1) >= 12000.0f) break;
        float4 av = a4[hq];
        float aa[4] = {av.x, av.y, av.z, av.w};
        #pragma unroll
        for (int j = 0; j < 4; ++j) {
            float h  = (float)(hq * 4 + j + 1);
            float hf = f0v * h;
            float fac = 1.0f;
            #pragma unroll
            for (int f = 0; f < NFMT; ++f) {
                float d = hf - freq[f];
                fac *= 1.0f + __fdividef(c1[f], fmaf(d, d, c2[f]));
            }
            float ar = rev_f * h;
            ar = __builtin_amdgcn_fractf(ar);          // arg in revolutions, [0,1)
            float s  = __builtin_amdgcn_sinf(ar);      // sin(2*pi*ar)
            float m  = (hf < 12000.0f) ? 1.0f : 0.0f;
            acc = fmaf(s * aa[j], fac * m, acc);
        }
    }
    if (!(f0v > 0.0f)) acc = 0.0f;   // voiced mask
    out[b * NT + t] = acc;
}

extern "C" void kernel_launch(void* const* d_in, const int* in_sizes, int n_in,
                              void* d_out, int out_size, void* d_ws, size_t ws_size,
                              hipStream_t stream) {
    const float* f0    = (const float*)d_in[0];
    const float* amps  = (const float*)d_in[1];
    const float* ffq   = (const float*)d_in[2];
    const float* fbw   = (const float*)d_in[3];
    const float* fam   = (const float*)d_in[4];
    const float* initp = (const float*)d_in[5];
    float* out = (float*)d_out;

    double* part = (double*)d_ws;           // NB*NCH doubles
    double* offs = part + NB * NCH;         // NB*NCH doubles

    dim3 grid(NCH, NB);
    k_partial<<<grid, CT, 0, stream>>>(f0, part);
    k_scan<<<NB, 64, 0, stream>>>(part, offs, initp, out + NB * NT);
    k_main<<<grid, CT, 0, stream>>>(f0, amps, ffq, fbw, fam, initp, offs, out);
}

// Round 2
// 48.470 us; speedup vs baseline: 1.4042x; 1.4042x over previous
//
#include <hip/hip_runtime.h>
#include <math.h>

#define SRATE   24000.0
#define NB      8
#define NT      48000
#define NH      60
#define NC      100
#define NFMT    5
#define CTS     64                        // timesteps per block
#define NCH     (NT / CTS)                // 750 chunks per batch
#define TWO_PI  6.283185307179586476925286766559

// ---------------- kernel 1: per-chunk f0 sums (double) ----------------
// 256 threads = 4 waves, each wave reduces one 64-timestep chunk.
__global__ __launch_bounds__(256) void k_partial(const float* __restrict__ f0,
                                                 double* __restrict__ part) {
    int b = blockIdx.y;
    int ch = blockIdx.x * 4 + (threadIdx.x >> 6);
    int lane = threadIdx.x & 63;
    if (ch < NCH) {
        int t = ch * CTS + lane;
        double q = (double)f0[b * NT + t];
        #pragma unroll
        for (int off = 32; off > 0; off >>= 1)
            q += __shfl_down(q, off, 64);
        if (lane == 0) part[b * NCH + ch] = q;
    }
}

// ------- kernel 2: per-batch exclusive scan of chunk sums + final phase -------
__global__ __launch_bounds__(64) void k_scan(const double* __restrict__ part,
                                             double* __restrict__ offs,
                                             const float* __restrict__ initp,
                                             float* __restrict__ outf) {
    int b = blockIdx.x;
    int lane = threadIdx.x;
    double carry = 0.0;
    for (int base = 0; base < NCH; base += 64) {
        int i = base + lane;
        double v = (i < NCH) ? part[b * NCH + i] : 0.0;
        double inc = v;
        #pragma unroll
        for (int off = 1; off < 64; off <<= 1) {
            double n = __shfl_up(inc, off, 64);
            if (lane >= off) inc += n;
        }
        double excl = __shfl_up(inc, 1, 64);
        if (lane == 0) excl = 0.0;
        if (i < NCH) offs[b * NCH + i] = carry + excl;
        carry += __shfl(inc, 63, 64);
    }
    if (lane == 0) {
        double rev = carry / SRATE + (double)initp[b] * (1.0 / TWO_PI);
        double fr = rev - floor(rev);
        outf[b] = (float)(fr * TWO_PI);
    }
}

// ---------------- kernel 3: main synthesis ----------------
// 256 threads. 4 lanes per timestep (j = tid&3 indexes float4s of one row)
// -> each group's load is one fully-consumed 64B cache line.
__global__ __launch_bounds__(256) void k_main(const float* __restrict__ f0,
                                              const float* __restrict__ amps,
                                              const float* __restrict__ ffq,
                                              const float* __restrict__ fbw,
                                              const float* __restrict__ fam,
                                              const float* __restrict__ initp,
                                              const double* __restrict__ offs,
                                              float* __restrict__ out) {
    int b = blockIdx.y, ch = blockIdx.x;
    int tid = threadIdx.x;

    __shared__ float s_rev[CTS];
    __shared__ float s_f0[CTS];
    __shared__ float s_cf[CTS][17];   // [0..4]=freq, [5..9]=c1(=a*bw^2), [10..14]=c2(=bw^2)

    if (tid < CTS) {
        int t = ch * CTS + tid;
        float f0v = f0[b * NT + t];
        // wave-level inclusive scan (double)
        double inc = (double)f0v;
        #pragma unroll
        for (int off = 1; off < 64; off <<= 1) {
            double n = __shfl_up(inc, off, 64);
            if (tid >= off) inc += n;
        }
        double pre = offs[b * NCH + ch];
        double rev = (pre + inc) / SRATE + (double)initp[b] * (1.0 / TWO_PI);
        double fr = rev - floor(rev);
        s_rev[tid] = (float)fr;
        s_f0[tid] = f0v;

        // formant track lerp (align_corners=True)
        double srcd = (double)t * (99.0 / 47999.0);
        int i0 = (int)srcd;
        if (i0 > NC - 2) i0 = NC - 2;
        float frac = (float)(srcd - (double)i0);
        float omf = 1.0f - frac;
        const float* Fq = ffq + (b * NC + i0) * NFMT;
        const float* Bw = fbw + (b * NC + i0) * NFMT;
        const float* Am = fam + (b * NC + i0) * NFMT;
        #pragma unroll
        for (int f = 0; f < NFMT; ++f) {
            float fq = Fq[f] * omf + Fq[NFMT + f] * frac;
            float bw = Bw[f] * omf + Bw[NFMT + f] * frac;
            float am = Am[f] * omf + Am[NFMT + f] * frac;
            s_cf[tid][f]      = fq;
            s_cf[tid][5 + f]  = am * bw * bw;
            s_cf[tid][10 + f] = bw * bw;
        }
    }
    __syncthreads();

    int g = tid >> 2;          // local timestep
    int j = tid & 3;           // float4 slot within row-chunk
    int t = ch * CTS + g;
    float f0v   = s_f0[g];
    float rev_f = s_rev[g];
    float freq[NFMT], c1[NFMT], c2[NFMT];
    #pragma unroll
    for (int f = 0; f < NFMT; ++f) {
        freq[f] = s_cf[g][f];
        c1[f]   = s_cf[g][5 + f];
        c2[f]   = s_cf[g][10 + f];
    }

    const float4* row = (const float4*)(amps + ((size_t)(b * NT) + (size_t)t) * NH);
    float acc = 0.0f;
    #pragma unroll
    for (int i = 0; i < 4; ++i) {                    // 16 harmonics per iter
        if (f0v * (float)(i * 16 + 1) >= 12000.0f) break;   // group-uniform exit
        int hbase = i * 16 + j * 4;                  // 0-indexed first harmonic
        if (hbase < NH) {
            float4 av = row[i * 4 + j];
            float aa[4] = {av.x, av.y, av.z, av.w};
            #pragma unroll
            for (int k = 0; k < 4; ++k) {
                float h  = (float)(hbase + k + 1);
                float hf = f0v * h;
                float fac = 1.0f;
                #pragma unroll
                for (int f = 0; f < NFMT; ++f) {
                    float d = hf - freq[f];
                    fac *= fmaf(c1[f], __builtin_amdgcn_rcpf(fmaf(d, d, c2[f])), 1.0f);
                }
                float ar = __builtin_amdgcn_fractf(rev_f * h);
                float s  = __builtin_amdgcn_sinf(ar);      // sin(2*pi*ar)
                float m  = (hf < 12000.0f) ? 1.0f : 0.0f;
                acc = fmaf(s * aa[k], fac * m, acc);
            }
        }
    }
    // reduce across the 4 lanes of the group
    acc += __shfl_xor(acc, 1, 64);
    acc += __shfl_xor(acc, 2, 64);
    if (j == 0) {
        if (!(f0v > 0.0f)) acc = 0.0f;
        out[b * NT + t] = acc;
    }
}

extern "C" void kernel_launch(void* const* d_in, const int* in_sizes, int n_in,
                              void* d_out, int out_size, void* d_ws, size_t ws_size,
                              hipStream_t stream) {
    const float* f0    = (const float*)d_in[0];
    const float* amps  = (const float*)d_in[1];
    const float* ffq   = (const float*)d_in[2];
    const float* fbw   = (const float*)d_in[3];
    const float* fam   = (const float*)d_in[4];
    const float* initp = (const float*)d_in[5];
    float* out = (float*)d_out;

    double* part = (double*)d_ws;           // NB*NCH doubles
    double* offs = part + NB * NCH;         // NB*NCH doubles

    dim3 gpart((NCH + 3) / 4, NB);
    k_partial<<<gpart, 256, 0, stream>>>(f0, part);
    k_scan<<<NB, 64, 0, stream>>>(part, offs, initp, out + NB * NT);
    dim3 gmain(NCH, NB);
    k_main<<<gmain, 256, 0, stream>>>(f0, amps, ffq, fbw, fam, initp, offs, out);
}

// Round 4
// 48.316 us; speedup vs baseline: 1.4087x; 1.0032x over previous
//
#include <hip/hip_runtime.h>
#include <math.h>

#define SRATE   24000.0
#define NB      8
#define NT      48000
#define NH      60
#define NC      100
#define NFMT    5
#define CTS     64                        // timesteps per chunk
#define NCH     (NT / CTS)                // 750 chunks per batch
#define TWO_PI  6.283185307179586476925286766559

// ---------------- kernel 1: per-chunk f0 sums (double) ----------------
__global__ __launch_bounds__(256) void k_partial(const float* __restrict__ f0,
                                                 double* __restrict__ part) {
    int b = blockIdx.y;
    int ch = blockIdx.x * 4 + (threadIdx.x >> 6);
    int lane = threadIdx.x & 63;
    if (ch < NCH) {
        int t = ch * CTS + lane;
        double q = (double)f0[b * NT + t];
        #pragma unroll
        for (int off = 32; off > 0; off >>= 1)
            q += __shfl_down(q, off, 64);
        if (lane == 0) part[b * NCH + ch] = q;
    }
}

// ------- kernel 2: per-batch exclusive scan of chunk sums + final phase -------
__global__ __launch_bounds__(64) void k_scan(const double* __restrict__ part,
                                             double* __restrict__ offs,
                                             const float* __restrict__ initp,
                                             float* __restrict__ outf) {
    int b = blockIdx.x;
    int lane = threadIdx.x;
    double carry = 0.0;
    for (int base = 0; base < NCH; base += 64) {
        int i = base + lane;
        double v = (i < NCH) ? part[b * NCH + i] : 0.0;
        double inc = v;
        #pragma unroll
        for (int off = 1; off < 64; off <<= 1) {
            double n = __shfl_up(inc, off, 64);
            if (lane >= off) inc += n;
        }
        double excl = __shfl_up(inc, 1, 64);
        if (lane == 0) excl = 0.0;
        if (i < NCH) offs[b * NCH + i] = carry + excl;
        carry += __shfl(inc, 63, 64);
    }
    if (lane == 0) {
        double rev = carry * (1.0 / SRATE) + (double)initp[b] * (1.0 / TWO_PI);
        double fr = rev - floor(rev);
        outf[b] = (float)(fr * TWO_PI);
    }
}

// ---------------- kernel 3: main synthesis ----------------
// 256 threads = 4 independent waves. Each wave redundantly preprocesses all
// 64 timesteps of the chunk (lane = timestep), then computes 16 timesteps
// x 4 lanes each. Wave w owns timesteps w*16 .. w*16+15. No LDS, no barriers.
__global__ __launch_bounds__(256) void k_main(const float* __restrict__ f0,
                                              const float* __restrict__ amps,
                                              const float* __restrict__ ffq,
                                              const float* __restrict__ fbw,
                                              const float* __restrict__ fam,
                                              const float* __restrict__ initp,
                                              const double* __restrict__ offs,
                                              float* __restrict__ out) {
    int b = blockIdx.y, ch = blockIdx.x;
    int wv   = threadIdx.x >> 6;       // wave id 0..3
    int lane = threadIdx.x & 63;
    int g = wv * 16 + (lane >> 2);     // compute timestep within chunk (0..63)
    int j = lane & 3;                  // float4 slot within row
    int t_pre = ch * CTS + lane;       // preamble timestep (one per lane)
    int t_g   = ch * CTS + g;          // compute timestep

    // --- f0 + early group predicate (so amp loads can issue ASAP) ---
    float f0v = f0[b * NT + t_pre];
    float f0s = f0v * (1.0f / 256.0f);             // exact scale by 2^-8
    float f0s_g = __shfl(f0s, g, 64);

    // --- amplitude loads: 4 lanes per row, one fully-consumed 64B line each ---
    const float4* row = (const float4*)(amps + ((size_t)b * NT + (size_t)t_g) * NH);
    float4 q[4];
    q[0] = row[j];
    q[1] = row[4 + j];
    q[2] = make_float4(0.f, 0.f, 0.f, 0.f);
    q[3] = make_float4(0.f, 0.f, 0.f, 0.f);
    if (f0s_g * 33.0f < 46.875f) q[2] = row[8 + j];            // any of h 33..48 below nyq
    if (j < 3 && f0s_g * 49.0f < 46.875f) q[3] = row[12 + j];  // h 49..60 (j==3 would be OOB)

    // --- double-precision phase scan for timestep t_pre ---
    double inc = (double)f0v;
    #pragma unroll
    for (int off = 1; off < 64; off <<= 1) {
        double n = __shfl_up(inc, off, 64);
        if (lane >= off) inc += n;
    }
    double pre = offs[b * NCH + ch];
    double rev = (pre + inc) * (1.0 / SRATE) + (double)initp[b] * (1.0 / TWO_PI);
    float rev_f = (float)(rev - floor(rev));       // phase in revolutions, [0,1)

    // --- formant lerp for timestep t_pre, prescaled by 2^-8 / 2^-16 ---
    double srcd = (double)t_pre * (99.0 / 47999.0);
    int i0 = (int)srcd;
    if (i0 > NC - 2) i0 = NC - 2;
    float frac = (float)(srcd - (double)i0);
    float omf = 1.0f - frac;
    const float* Fq = ffq + (b * NC + i0) * NFMT;
    const float* Bw = fbw + (b * NC + i0) * NFMT;
    const float* Am = fam + (b * NC + i0) * NFMT;
    float fqs[NFMT], c1s[NFMT], c2s[NFMT];
    #pragma unroll
    for (int f = 0; f < NFMT; ++f) {
        float fq = Fq[f] * omf + Fq[NFMT + f] * frac;
        float bw = Bw[f] * omf + Bw[NFMT + f] * frac;
        float am = Am[f] * omf + Am[NFMT + f] * frac;
        float bws = bw * (1.0f / 256.0f);
        fqs[f] = fq * (1.0f / 256.0f);
        c2s[f] = bws * bws;
        c1s[f] = am * c2s[f];
    }

    // --- redistribute preamble values from lane g (wave holds all 64 steps) ---
    float rev_g = __shfl(rev_f, g, 64);
    float fq_g[NFMT], c1_g[NFMT], c2_g[NFMT];
    #pragma unroll
    for (int f = 0; f < NFMT; ++f) {
        fq_g[f] = __shfl(fqs[f], g, 64);
        c1_g[f] = __shfl(c1s[f], g, 64);
        c2_g[f] = __shfl(c2s[f], g, 64);
    }

    // --- straight-line harmonic accumulation (16 harmonics per lane) ---
    float acc = 0.0f;
    float j4 = (float)(j * 4);
    #pragma unroll
    for (int i = 0; i < 4; ++i) {
        float aa[4] = {q[i].x, q[i].y, q[i].z, q[i].w};
        #pragma unroll
        for (int k = 0; k < 4; ++k) {
            float hfl = (float)(i * 16 + k + 1) + j4;     // harmonic number
            float hs = f0s_g * hfl;                        // f0*h * 2^-8
            float pN = 1.0f, pD = 1.0f;
            #pragma unroll
            for (int f = 0; f < NFMT; ++f) {
                float d = hs - fq_g[f];
                float e = fmaf(d, d, c2_g[f]);
                pN *= (e + c1_g[f]);
                pD *= e;
            }
            float fac = pN * __builtin_amdgcn_rcpf(pD);
            float ar = __builtin_amdgcn_fractf(rev_g * hfl);
            float sn = __builtin_amdgcn_sinf(ar);          // sin(2*pi*ar)
            float fm = (hs < 46.875f) ? fac : 0.0f;        // nyquist mask (12000*2^-8)
            acc = fmaf(sn * aa[k], fm, acc);
        }
    }

    // --- reduce the 4 lanes of the group, write ---
    acc += __shfl_xor(acc, 1, 64);
    acc += __shfl_xor(acc, 2, 64);
    if (j == 0) {
        if (!(f0s_g > 0.0f)) acc = 0.0f;                   // voiced mask
        out[b * NT + t_g] = acc;
    }
}

extern "C" void kernel_launch(void* const* d_in, const int* in_sizes, int n_in,
                              void* d_out, int out_size, void* d_ws, size_t ws_size,
                              hipStream_t stream) {
    const float* f0    = (const float*)d_in[0];
    const float* amps  = (const float*)d_in[1];
    const float* ffq   = (const float*)d_in[2];
    const float* fbw   = (const float*)d_in[3];
    const float* fam   = (const float*)d_in[4];
    const float* initp = (const float*)d_in[5];
    float* out = (float*)d_out;

    double* part = (double*)d_ws;           // NB*NCH doubles
    double* offs = part + NB * NCH;         // NB*NCH doubles

    dim3 gpart((NCH + 3) / 4, NB);
    k_partial<<<gpart, 256, 0, stream>>>(f0, part);
    k_scan<<<NB, 64, 0, stream>>>(part, offs, initp, out + NB * NT);
    dim3 gmain(NCH, NB);
    k_main<<<gmain, 256, 0, stream>>>(f0, amps, ffq, fbw, fam, initp, offs, out);
}

// Round 5
// 40.412 us; speedup vs baseline: 1.6842x; 1.1956x over previous
//
#include <hip/hip_runtime.h>
#include <math.h>

#define SRATE   24000.0
#define NB      8
#define NT      48000
#define NH      60
#define NC      100
#define NFMT    5
#define CTS     64                        // timesteps per chunk
#define NCH     (NT / CTS)                // 750 chunks per batch
#define TWO_PI  6.283185307179586476925286766559

typedef float v2f __attribute__((ext_vector_type(2)));

// ---------------- kernel 1: per-chunk f0 sums (double) ----------------
__global__ __launch_bounds__(256) void k_partial(const float* __restrict__ f0,
                                                 double* __restrict__ part) {
    int b = blockIdx.y;
    int ch = blockIdx.x * 4 + (threadIdx.x >> 6);
    int lane = threadIdx.x & 63;
    if (ch < NCH) {
        int t = ch * CTS + lane;
        double q = (double)f0[b * NT + t];
        #pragma unroll
        for (int off = 32; off > 0; off >>= 1)
            q += __shfl_down(q, off, 64);
        if (lane == 0) part[b * NCH + ch] = q;
    }
}

// ------- kernel 2: per-batch block scan of 750 chunk sums + final phase -------
__global__ __launch_bounds__(256) void k_scan(const double* __restrict__ part,
                                              double* __restrict__ offs,
                                              const float* __restrict__ initp,
                                              float* __restrict__ outf) {
    int b = blockIdx.x;
    int tid = threadIdx.x;
    int lane = tid & 63, wv = tid >> 6;
    int base = tid * 3;
    double v0 = (base     < NCH) ? part[b * NCH + base    ] : 0.0;
    double v1 = (base + 1 < NCH) ? part[b * NCH + base + 1] : 0.0;
    double v2 = (base + 2 < NCH) ? part[b * NCH + base + 2] : 0.0;
    double s = v0 + v1 + v2;
    double inc = s;
    #pragma unroll
    for (int off = 1; off < 64; off <<= 1) {
        double n = __shfl_up(inc, off, 64);
        if (lane >= off) inc += n;
    }
    __shared__ double wtot[4];
    if (lane == 63) wtot[wv] = inc;
    __syncthreads();
    double woff = 0.0;
    #pragma unroll
    for (int w = 0; w < 4; ++w)
        if (w < wv) woff += wtot[w];
    double excl = woff + inc - s;              // exclusive prefix for this thread
    if (base     < NCH) offs[b * NCH + base    ] = excl;
    if (base + 1 < NCH) offs[b * NCH + base + 1] = excl + v0;
    if (base + 2 < NCH) offs[b * NCH + base + 2] = excl + v0 + v1;
    if (tid == 255) {
        double carry = woff + inc;             // grand total
        double rev = carry * (1.0 / SRATE) + (double)initp[b] * (1.0 / TWO_PI);
        double fr = rev - floor(rev);
        outf[b] = (float)(fr * TWO_PI);
    }
}

// ---------------- kernel 3: main synthesis ----------------
// 256 threads = 4 waves. Wave w owns timesteps w*16..w*16+15 (4 lanes each).
// Preamble per wave: lane = timestep for the f64 scan; formant lerp computed
// directly for the group timestep on all lanes. Inner loop in packed fp32
// (v_pk_*) over harmonic pairs.
__global__ __launch_bounds__(256) void k_main(const float* __restrict__ f0,
                                              const float* __restrict__ amps,
                                              const float* __restrict__ ffq,
                                              const float* __restrict__ fbw,
                                              const float* __restrict__ fam,
                                              const float* __restrict__ initp,
                                              const double* __restrict__ offs,
                                              float* __restrict__ out) {
    int b = blockIdx.y, ch = blockIdx.x;
    int wv   = threadIdx.x >> 6;
    int lane = threadIdx.x & 63;
    int g = wv * 16 + (lane >> 2);     // compute timestep within chunk (0..63)
    int j = lane & 3;                  // float4 slot within row
    int t_pre = ch * CTS + lane;       // preamble timestep (one per lane)
    int t_g   = ch * CTS + g;          // compute timestep

    float f0v = f0[b * NT + t_pre];
    float f0s = f0v * (1.0f / 256.0f);             // exact scale by 2^-8
    float f0s_g = __shfl(f0s, g, 64);

    // --- amplitude loads: 4 lanes per row, one fully-consumed 64B line each ---
    const float4* row = (const float4*)(amps + ((size_t)b * NT + (size_t)t_g) * NH);
    float4 q[4];
    q[0] = row[j];
    q[1] = row[4 + j];
    q[2] = make_float4(0.f, 0.f, 0.f, 0.f);
    q[3] = make_float4(0.f, 0.f, 0.f, 0.f);
    if (f0s_g * 33.0f < 46.875f) q[2] = row[8 + j];            // any of h 33..48 below nyq
    if (j < 3 && f0s_g * 49.0f < 46.875f) q[3] = row[12 + j];  // h 49..60 (j==3 would be OOB)

    // --- double-precision phase scan for timestep t_pre ---
    double inc = (double)f0v;
    #pragma unroll
    for (int off = 1; off < 64; off <<= 1) {
        double n = __shfl_up(inc, off, 64);
        if (lane >= off) inc += n;
    }
    double pre = offs[b * NCH + ch];
    double rev = (pre + inc) * (1.0 / SRATE) + (double)initp[b] * (1.0 / TWO_PI);
    float rev_f = (float)(rev - floor(rev));       // phase in revolutions, [0,1)
    float rev_g = __shfl(rev_f, g, 64);

    // --- formant lerp for the GROUP timestep t_g (all 4 lanes compute it) ---
    double srcd = (double)t_g * (99.0 / 47999.0);
    int i0 = (int)srcd;
    if (i0 > NC - 2) i0 = NC - 2;
    float frac = (float)(srcd - (double)i0);
    float omf = 1.0f - frac;
    const float* Fq = ffq + (b * NC + i0) * NFMT;
    const float* Bw = fbw + (b * NC + i0) * NFMT;
    const float* Am = fam + (b * NC + i0) * NFMT;
    float fq_g[NFMT], c1_g[NFMT], c2_g[NFMT];
    #pragma unroll
    for (int f = 0; f < NFMT; ++f) {
        float fq = Fq[f] * omf + Fq[NFMT + f] * frac;
        float bw = Bw[f] * omf + Bw[NFMT + f] * frac;
        float am = Am[f] * omf + Am[NFMT + f] * frac;
        float bws = bw * (1.0f / 256.0f);
        fq_g[f] = fq * (1.0f / 256.0f);
        c2_g[f] = bws * bws;
        c1_g[f] = am * c2_g[f];
    }

    // --- packed-fp32 harmonic accumulation: 8 pairs per lane ---
    v2f acc2 = {0.0f, 0.0f};
    float j4 = (float)(j * 4);
    #pragma unroll
    for (int i = 0; i < 4; ++i) {
        float aq[4] = {q[i].x, q[i].y, q[i].z, q[i].w};
        #pragma unroll
        for (int p = 0; p < 2; ++p) {
            float h0 = (float)(i * 16 + p * 2 + 1) + j4;
            v2f hfl = {h0, h0 + 1.0f};
            v2f aa  = {aq[p * 2], aq[p * 2 + 1]};
            v2f hs  = f0s_g * hfl;                 // f0*h * 2^-8 (pk mul)
            v2f pN  = {1.0f, 1.0f};
            v2f pD  = {1.0f, 1.0f};
            #pragma unroll
            for (int f = 0; f < NFMT; ++f) {
                v2f d = hs - fq_g[f];
                v2f e = d * d + c2_g[f];           // pk fma
                pN *= (e + c1_g[f]);
                pD *= e;
            }
            v2f rp;
            rp.x = __builtin_amdgcn_rcpf(pD.x);
            rp.y = __builtin_amdgcn_rcpf(pD.y);
            v2f fac = pN * rp;
            v2f ar = rev_g * hfl;
            v2f sn;
            sn.x = __builtin_amdgcn_sinf(__builtin_amdgcn_fractf(ar.x));
            sn.y = __builtin_amdgcn_sinf(__builtin_amdgcn_fractf(ar.y));
            v2f fm;
            fm.x = (hs.x < 46.875f) ? fac.x : 0.0f;   // nyquist mask (12000*2^-8)
            fm.y = (hs.y < 46.875f) ? fac.y : 0.0f;
            acc2 += (sn * aa) * fm;
        }
    }
    float acc = acc2.x + acc2.y;
    acc += __shfl_xor(acc, 1, 64);
    acc += __shfl_xor(acc, 2, 64);
    if (j == 0) {
        if (!(f0s_g > 0.0f)) acc = 0.0f;               // voiced mask
        out[b * NT + t_g] = acc;
    }
}

extern "C" void kernel_launch(void* const* d_in, const int* in_sizes, int n_in,
                              void* d_out, int out_size, void* d_ws, size_t ws_size,
                              hipStream_t stream) {
    const float* f0    = (const float*)d_in[0];
    const float* amps  = (const float*)d_in[1];
    const float* ffq   = (const float*)d_in[2];
    const float* fbw   = (const float*)d_in[3];
    const float* fam   = (const float*)d_in[4];
    const float* initp = (const float*)d_in[5];
    float* out = (float*)d_out;

    double* part = (double*)d_ws;           // NB*NCH doubles
    double* offs = part + NB * NCH;         // NB*NCH doubles

    dim3 gpart((NCH + 3) / 4, NB);
    k_partial<<<gpart, 256, 0, stream>>>(f0, part);
    k_scan<<<NB, 256, 0, stream>>>(part, offs, initp, out + NB * NT);
    dim3 gmain(NCH, NB);
    k_main<<<gmain, 256, 0, stream>>>(f0, amps, ffq, fbw, fam, initp, offs, out);
}